// Round 3
// baseline (1862.188 us; speedup 1.0000x reference)
//
#include <hip/hip_runtime.h>

typedef short short8 __attribute__((ext_vector_type(8)));
typedef float f32x4 __attribute__((ext_vector_type(4)));

#define MFMA_BF16(a, b, c) __builtin_amdgcn_mfma_f32_16x16x32_bf16((a), (b), (c), 0, 0, 0)

__device__ __forceinline__ unsigned short f2bf(float f) {
    unsigned u = __float_as_uint(f);
    u += 0x7fff + ((u >> 16) & 1);      // round-to-nearest-even
    return (unsigned short)(u >> 16);
}
__device__ __forceinline__ float bf2f(unsigned short h) {
    return __uint_as_float(((unsigned)h) << 16);
}

// ---------------------------------------------------------------------------
// Split fp32 -> (hi, lo) bf16 planes. Up to 7 jobs fused via blockIdx.z.
// x ~= bf2f(hi) + bf2f(lo), |residual| <~ 2^-18 |x|.
// ---------------------------------------------------------------------------
struct ConvJob  { const float* src; short* hi; short* lo; int n8; };
struct ConvArgs { ConvJob j[7]; };

__global__ __launch_bounds__(256) void conv_split(ConvArgs a) {
    ConvJob jb = a.j[blockIdx.z];
    const int n8 = jb.n8;
    for (int i = blockIdx.x * blockDim.x + threadIdx.x; i < n8;
         i += gridDim.x * blockDim.x) {
        const float4* s = (const float4*)jb.src + (size_t)i * 2;
        float4 x0 = s[0], x1 = s[1];
        float xs[8] = {x0.x, x0.y, x0.z, x0.w, x1.x, x1.y, x1.z, x1.w};
        short8 h, l;
#pragma unroll
        for (int jj = 0; jj < 8; ++jj) {
            unsigned short hh = f2bf(xs[jj]);
            h[jj] = (short)hh;
            l[jj] = (short)f2bf(xs[jj] - bf2f(hh));
        }
        *(short8*)(jb.hi + (size_t)i * 8) = h;
        *(short8*)(jb.lo + (size_t)i * 8) = l;
    }
}

// ---------------------------------------------------------------------------
// bf16x3-split MFMA GEMM: C[M][512] = X[M][512] * W[512][512]^T (+bias).
// BM=BN=128, BK=32, 256 thr = 4 waves (2x2), 64x64 per wave, 4x4 frags of
// 16x16x32. W always pre-split bf16 planes; X either pre-split (BF16=true)
// or fp32 converted in staging (BF16=false). blockIdx.z picks a triple.
// LDS row stride PLD=40 shorts (80 B): staging writes & frag reads 2-way.
// mfma_f32_16x16x32_bf16 layout (lane=16g+r): A[r][8g+j], B[8g+j][r],
// D[4g+i][r]  (C/D guide-verified m89/m91).
// ---------------------------------------------------------------------------
#define PBK 32
#define PLD 40

template<bool BF16>
__global__ __launch_bounds__(256) void mfma_gemm(
    const void* Xa0, const void* Xb0, const short* Wh0, const short* Wl0, float* C0,
    const void* Xa1, const void* Xb1, const short* Wh1, const short* Wl1, float* C1,
    const void* Xa2, const void* Xb2, const short* Wh2, const short* Wl2, float* C2,
    const float* __restrict__ bias)
{
    const void* Xa; const void* Xb; const short* Whp; const short* Wlp; float* C;
    if (blockIdx.z == 0)      { Xa = Xa0; Xb = Xb0; Whp = Wh0; Wlp = Wl0; C = C0; }
    else if (blockIdx.z == 1) { Xa = Xa1; Xb = Xb1; Whp = Wh1; Wlp = Wl1; C = C1; }
    else                      { Xa = Xa2; Xb = Xb2; Whp = Wh2; Wlp = Wl2; C = C2; }

    const float* Xf = (const float*)Xa;
    const short* Xh = (const short*)Xa;
    const short* Xl = (const short*)Xb;

    __shared__ __align__(16) short Ah[128 * PLD];
    __shared__ __align__(16) short Al[128 * PLD];
    __shared__ __align__(16) short Bh[128 * PLD];
    __shared__ __align__(16) short Bl[128 * PLD];

    const int tid = threadIdx.x;
    const int rowBase = blockIdx.x * 128;
    const int colBase = blockIdx.y * 128;
    const int rs = tid >> 1;            // staging row 0..127
    const int kh = tid & 1;             // 16-element k-half
    const int lane = tid & 63;
    const int wv = tid >> 6;
    const int wm = (wv >> 1) * 64;      // wave row offset
    const int wn = (wv & 1) * 64;       // wave col offset
    const int g = lane >> 4, r = lane & 15;

    f32x4 acc[4][4];
#pragma unroll
    for (int i = 0; i < 4; ++i)
#pragma unroll
        for (int j = 0; j < 4; ++j) acc[i][j] = (f32x4)(0.f);

    short8 sAh0, sAh1, sAl0, sAl1, sBh0, sBh1, sBl0, sBl1;
    float4 sF0, sF1, sF2, sF3;

    auto loadRegs = [&](int kt) {
        const size_t aoff = (size_t)(rowBase + rs) * 512 + kt * PBK + kh * 16;
        const size_t boff = (size_t)(colBase + rs) * 512 + kt * PBK + kh * 16;
        if constexpr (BF16) {
            sAh0 = *(const short8*)(Xh + aoff); sAh1 = *(const short8*)(Xh + aoff + 8);
            sAl0 = *(const short8*)(Xl + aoff); sAl1 = *(const short8*)(Xl + aoff + 8);
        } else {
            sF0 = *(const float4*)(Xf + aoff);      sF1 = *(const float4*)(Xf + aoff + 4);
            sF2 = *(const float4*)(Xf + aoff + 8);  sF3 = *(const float4*)(Xf + aoff + 12);
        }
        sBh0 = *(const short8*)(Whp + boff); sBh1 = *(const short8*)(Whp + boff + 8);
        sBl0 = *(const short8*)(Wlp + boff); sBl1 = *(const short8*)(Wlp + boff + 8);
    };

    auto stageLDS = [&]() {
        const int lb = rs * PLD + kh * 16;
        if constexpr (BF16) {
            *(short8*)&Ah[lb] = sAh0; *(short8*)&Ah[lb + 8] = sAh1;
            *(short8*)&Al[lb] = sAl0; *(short8*)&Al[lb + 8] = sAl1;
        } else {
            float xs[16] = {sF0.x, sF0.y, sF0.z, sF0.w, sF1.x, sF1.y, sF1.z, sF1.w,
                            sF2.x, sF2.y, sF2.z, sF2.w, sF3.x, sF3.y, sF3.z, sF3.w};
            short8 h0, h1, l0, l1;
#pragma unroll
            for (int jj = 0; jj < 8; ++jj) {
                unsigned short ha = f2bf(xs[jj]);
                h0[jj] = (short)ha; l0[jj] = (short)f2bf(xs[jj] - bf2f(ha));
                unsigned short hb = f2bf(xs[8 + jj]);
                h1[jj] = (short)hb; l1[jj] = (short)f2bf(xs[8 + jj] - bf2f(hb));
            }
            *(short8*)&Ah[lb] = h0; *(short8*)&Ah[lb + 8] = h1;
            *(short8*)&Al[lb] = l0; *(short8*)&Al[lb + 8] = l1;
        }
        *(short8*)&Bh[lb] = sBh0; *(short8*)&Bh[lb + 8] = sBh1;
        *(short8*)&Bl[lb] = sBl0; *(short8*)&Bl[lb + 8] = sBl1;
    };

    loadRegs(0);

    for (int kt = 0; kt < 16; ++kt) {
        __syncthreads();                // previous compute done
        stageLDS();
        __syncthreads();
        if (kt < 15) loadRegs(kt + 1);  // prefetch retires under MFMA

        short8 fah[4], fal[4], fbh[4], fbl[4];
#pragma unroll
        for (int fm = 0; fm < 4; ++fm) {
            const int off = (wm + fm * 16 + r) * PLD + g * 8;
            fah[fm] = *(const short8*)&Ah[off];
            fal[fm] = *(const short8*)&Al[off];
        }
#pragma unroll
        for (int fn = 0; fn < 4; ++fn) {
            const int off = (wn + fn * 16 + r) * PLD + g * 8;
            fbh[fn] = *(const short8*)&Bh[off];
            fbl[fn] = *(const short8*)&Bl[off];
        }
#pragma unroll
        for (int fm = 0; fm < 4; ++fm)
#pragma unroll
            for (int fn = 0; fn < 4; ++fn) {
                acc[fm][fn] = MFMA_BF16(fah[fm], fbh[fn], acc[fm][fn]);
                acc[fm][fn] = MFMA_BF16(fah[fm], fbl[fn], acc[fm][fn]);
                acc[fm][fn] = MFMA_BF16(fal[fm], fbh[fn], acc[fm][fn]);
            }
    }

    float bv[4];
#pragma unroll
    for (int fn = 0; fn < 4; ++fn)
        bv[fn] = bias ? bias[colBase + wn + fn * 16 + r] : 0.f;

#pragma unroll
    for (int fm = 0; fm < 4; ++fm)
#pragma unroll
        for (int fn = 0; fn < 4; ++fn) {
            const int col = colBase + wn + fn * 16 + r;
#pragma unroll
            for (int i = 0; i < 4; ++i) {
                const int row = rowBase + wm + fm * 16 + g * 4 + i;
                C[(size_t)row * 512 + col] = acc[fm][fn][i] + bv[fn];
            }
        }
}

// ---------------------------------------------------------------------------
// fp32 flash attention (audited r0/r1, unchanged). One block = 64 q-rows of
// one (b,h); 256 threads; online softmax; masked = -1e20 (matches reference
// incl. all-masked-row uniform limit). All LDS patterns 2-way (free).
// ---------------------------------------------------------------------------
#define AP 68

__global__ __launch_bounds__(256) void attn_fwd(
    const float* __restrict__ Qm, const float* __restrict__ Km,
    const float* __restrict__ Vm, const int* __restrict__ mask,
    float* __restrict__ Om)
{
    const int S = 2048, E = 512;
    const float scale = 0.04419417382415922f;  // 1/sqrt(512)

    __shared__ __align__(16) float Qs[64][AP];
    __shared__ __align__(16) float Ks[64][AP];
    __shared__ __align__(16) float Vs[64][AP];
    __shared__ __align__(16) float Ps[64][AP];
    __shared__ int Ms[64];

    const int tid = threadIdx.x;
    const int qt = blockIdx.x;
    const int bh = blockIdx.y;
    const int b = bh >> 3, h = bh & 7;
    const int qg = tid >> 4;
    const int kg = tid & 15;

    const float* qbase = Qm + (size_t)(b * S + qt * 64) * E + h * 64;
    const float* kbase = Km + (size_t)b * S * E + h * 64;
    const float* vbase = Vm + (size_t)b * S * E + h * 64;
    const int*   mbase = mask + b * S;

#pragma unroll
    for (int l = 0; l < 4; ++l) {
        const int id = tid + l * 256;
        const int row = id >> 4, c4 = (id & 15) << 2;
        *(float4*)&Qs[row][c4] = *(const float4*)&qbase[row * E + c4];
    }

    float m_[4], l_[4], acc[4][4];
#pragma unroll
    for (int i = 0; i < 4; ++i) {
        m_[i] = -3.0e38f; l_[i] = 0.f;
#pragma unroll
        for (int d = 0; d < 4; ++d) acc[i][d] = 0.f;
    }

    float4 gk[4], gv[4];
#pragma unroll
    for (int l = 0; l < 4; ++l) {
        const int id = tid + l * 256;
        const int row = id >> 4, c4 = (id & 15) << 2;
        gk[l] = *(const float4*)&kbase[row * E + c4];
        gv[l] = *(const float4*)&vbase[row * E + c4];
    }

    for (int kt = 0; kt < 32; ++kt) {
        __syncthreads();
#pragma unroll
        for (int l = 0; l < 4; ++l) {
            const int id = tid + l * 256;
            const int row = id >> 4, c4 = (id & 15) << 2;
            *(float4*)&Ks[row][c4] = gk[l];
            *(float4*)&Vs[row][c4] = gv[l];
        }
        if (tid < 64) Ms[tid] = mbase[kt * 64 + tid];
        __syncthreads();

        if (kt < 31) {
            const float* kb2 = kbase + (size_t)(kt + 1) * 64 * E;
            const float* vb2 = vbase + (size_t)(kt + 1) * 64 * E;
#pragma unroll
            for (int l = 0; l < 4; ++l) {
                const int id = tid + l * 256;
                const int row = id >> 4, c4 = (id & 15) << 2;
                gk[l] = *(const float4*)&kb2[row * E + c4];
                gv[l] = *(const float4*)&vb2[row * E + c4];
            }
        }

        float ev[4][4];
#pragma unroll
        for (int i = 0; i < 4; ++i)
#pragma unroll
            for (int c = 0; c < 4; ++c) ev[i][c] = 0.f;

#pragma unroll
        for (int e4 = 0; e4 < 16; ++e4) {
            float4 qv[4];
#pragma unroll
            for (int i = 0; i < 4; ++i)
                qv[i] = *(const float4*)&Qs[qg*4 + i][e4 << 2];
#pragma unroll
            for (int c = 0; c < 4; ++c) {
                const float4 kv = *(const float4*)&Ks[kg + (c << 4)][e4 << 2];
#pragma unroll
                for (int i = 0; i < 4; ++i)
                    ev[i][c] = fmaf(qv[i].x, kv.x, fmaf(qv[i].y, kv.y,
                               fmaf(qv[i].z, kv.z, fmaf(qv[i].w, kv.w, ev[i][c]))));
            }
        }

        int msk[4];
#pragma unroll
        for (int c = 0; c < 4; ++c) msk[c] = Ms[kg + (c << 4)];

        float mt[4];
#pragma unroll
        for (int i = 0; i < 4; ++i) {
#pragma unroll
            for (int c = 0; c < 4; ++c)
                ev[i][c] = msk[c] ? ev[i][c] * scale : -1.0e20f;
            mt[i] = fmaxf(fmaxf(ev[i][0], ev[i][1]), fmaxf(ev[i][2], ev[i][3]));
        }
#pragma unroll
        for (int d = 1; d < 16; d <<= 1)
#pragma unroll
            for (int i = 0; i < 4; ++i)
                mt[i] = fmaxf(mt[i], __shfl_xor(mt[i], d));

#pragma unroll
        for (int i = 0; i < 4; ++i) {
            const float mn = fmaxf(m_[i], mt[i]);
            const float alpha = __expf(m_[i] - mn);
            m_[i] = mn;
            float ps = 0.f;
#pragma unroll
            for (int c = 0; c < 4; ++c) {
                const float p = __expf(ev[i][c] - mn);
                ev[i][c] = p;
                ps += p;
            }
            l_[i] = l_[i] * alpha + ps;
#pragma unroll
            for (int d = 0; d < 4; ++d) acc[i][d] *= alpha;
#pragma unroll
            for (int c = 0; c < 4; ++c)
                Ps[qg*4 + i][kg + (c << 4)] = ev[i][c];
        }
        __syncthreads();

#pragma unroll
        for (int k4 = 0; k4 < 16; ++k4) {
            float pa[4][4];
#pragma unroll
            for (int i = 0; i < 4; ++i) {
                const float4 pv = *(const float4*)&Ps[qg*4 + i][k4 << 2];
                pa[i][0] = pv.x; pa[i][1] = pv.y; pa[i][2] = pv.z; pa[i][3] = pv.w;
            }
#pragma unroll
            for (int jj = 0; jj < 4; ++jj) {
                const float4 vv = *(const float4*)&Vs[(k4 << 2) + jj][kg << 2];
#pragma unroll
                for (int i = 0; i < 4; ++i) {
                    acc[i][0] = fmaf(pa[i][jj], vv.x, acc[i][0]);
                    acc[i][1] = fmaf(pa[i][jj], vv.y, acc[i][1]);
                    acc[i][2] = fmaf(pa[i][jj], vv.z, acc[i][2]);
                    acc[i][3] = fmaf(pa[i][jj], vv.w, acc[i][3]);
                }
            }
        }
    }

#pragma unroll
    for (int i = 0; i < 4; ++i) {
        float ls = l_[i];
#pragma unroll
        for (int d = 1; d < 16; d <<= 1) ls += __shfl_xor(ls, d);
        const float inv = 1.0f / ls;
        const int row = qt * 64 + qg * 4 + i;
        float4 o = make_float4(acc[i][0]*inv, acc[i][1]*inv, acc[i][2]*inv, acc[i][3]*inv);
        *(float4*)&Om[(size_t)(b * S + row) * E + h * 64 + (kg << 2)] = o;
    }
}

// ---------------------------------------------------------------------------
extern "C" void kernel_launch(void* const* d_in, const int* in_sizes, int n_in,
                              void* d_out, int out_size, void* d_ws, size_t ws_size,
                              hipStream_t stream) {
    const float* values = (const float*)d_in[0];
    const float* keys   = (const float*)d_in[1];
    const float* query  = (const float*)d_in[2];
    const int*   mask   = (const int*)d_in[3];
    const float* Wv     = (const float*)d_in[4];
    const float* Wk     = (const float*)d_in[5];
    const float* Wq     = (const float*)d_in[6];
    const float* Wo     = (const float*)d_in[7];
    const float* bo     = (const float*)d_in[8];
    float* out = (float*)d_out;

    const size_t MB = 1024 * 1024;
    char* w = (char*)d_ws;
    // fp32 buffers
    float* qb = (float*)(w);                // 16 MB
    float* kb = (float*)(w + 16 * MB);
    float* vb = (float*)(w + 32 * MB);
    float* ab = (float*)(w + 48 * MB);
    // weight bf16 planes (512 KB each) @64 MB
    short* Wqh = (short*)(w + 64 * MB);             short* Wql = Wqh + 262144;
    short* Wkh = Wql + 262144;                      short* Wkl = Wkh + 262144;
    short* Wvh = Wkl + 262144;                      short* Wvl = Wvh + 262144;
    short* Woh = Wvl + 262144;                      short* Wol = Woh + 262144;
    // big-ws path: X bf16 planes (8 MB each) @68 MB .. 116 MB
    short* Xqh = (short*)(w + 68 * MB);             short* Xql = Xqh + 4194304;
    short* Xkh = Xql + 4194304;                     short* Xkl = Xkh + 4194304;
    short* Xvh = Xkl + 4194304;                     short* Xvl = Xvh + 4194304;

    const bool big = ws_size >= 116 * MB;
    const int nW = 512 * 512 / 8;       // ConvJob n8 for a weight
    const int nX = 8192 * 512 / 8;      // ConvJob n8 for an activation

    ConvArgs ca = {};
    int nj = 0;
    ca.j[nj++] = {Wq, Wqh, Wql, nW};
    ca.j[nj++] = {Wk, Wkh, Wkl, nW};
    ca.j[nj++] = {Wv, Wvh, Wvl, nW};
    ca.j[nj++] = {Wo, Woh, Wol, nW};
    if (big) {
        ca.j[nj++] = {query,  Xqh, Xql, nX};
        ca.j[nj++] = {keys,   Xkh, Xkl, nX};
        ca.j[nj++] = {values, Xvh, Xvl, nX};
    }
    conv_split<<<dim3(256, 1, nj), 256, 0, stream>>>(ca);

    if (big) {
        mfma_gemm<true><<<dim3(64, 4, 3), 256, 0, stream>>>(
            Xqh, Xql, Wqh, Wql, qb,
            Xkh, Xkl, Wkh, Wkl, kb,
            Xvh, Xvl, Wvh, Wvl, vb, nullptr);
    } else {
        mfma_gemm<false><<<dim3(64, 4, 3), 256, 0, stream>>>(
            query,  nullptr, Wqh, Wql, qb,
            keys,   nullptr, Wkh, Wkl, kb,
            values, nullptr, Wvh, Wvl, vb, nullptr);
    }

    attn_fwd<<<dim3(32, 32), 256, 0, stream>>>(qb, kb, vb, mask, ab);

    if (big) {
        // split attention output into (reused) Xq planes, then MFMA out-proj
        ConvArgs cb = {};
        cb.j[0] = {ab, Xqh, Xql, nX};
        conv_split<<<dim3(256, 1, 1), 256, 0, stream>>>(cb);
        mfma_gemm<true><<<dim3(64, 4, 1), 256, 0, stream>>>(
            Xqh, Xql, Woh, Wol, out,
            Xqh, Xql, Woh, Wol, out,
            Xqh, Xql, Woh, Wol, out, bo);
    } else {
        mfma_gemm<false><<<dim3(64, 4, 1), 256, 0, stream>>>(
            ab, nullptr, Woh, Wol, out,
            ab, nullptr, Woh, Wol, out,
            ab, nullptr, Woh, Wol, out, bo);
    }
}

// Round 4
// 300.085 us; speedup vs baseline: 6.2055x; 6.2055x over previous
//
#include <hip/hip_runtime.h>

typedef short short8 __attribute__((ext_vector_type(8)));
typedef float f32x4 __attribute__((ext_vector_type(4)));
typedef float f32x16 __attribute__((ext_vector_type(16)));

#define MFMA16(a,b,c) __builtin_amdgcn_mfma_f32_16x16x32_bf16((a),(b),(c),0,0,0)
#define MFMA32(a,b,c) __builtin_amdgcn_mfma_f32_32x32x16_bf16((a),(b),(c),0,0,0)

__device__ __forceinline__ unsigned short f2bf(float f) {
    unsigned u = __float_as_uint(f);
    u += 0x7fff + ((u >> 16) & 1);      // rne
    return (unsigned short)(u >> 16);
}
__device__ __forceinline__ float bf2f(unsigned short h) {
    return __uint_as_float(((unsigned)h) << 16);
}

// ---------------------------------------------------------------------------
// fp32 -> (hi, lo) bf16 plane split for the 4 weight matrices.
// ---------------------------------------------------------------------------
struct ConvJob  { const float* src; short* hi; short* lo; int n8; };
struct ConvArgs { ConvJob j[4]; };

__global__ __launch_bounds__(256) void conv_split(ConvArgs a) {
    ConvJob jb = a.j[blockIdx.z];
    const int n8 = jb.n8;
    for (int i = blockIdx.x * blockDim.x + threadIdx.x; i < n8;
         i += gridDim.x * blockDim.x) {
        const float4* s = (const float4*)jb.src + (size_t)i * 2;
        float4 x0 = s[0], x1 = s[1];
        float xs[8] = {x0.x, x0.y, x0.z, x0.w, x1.x, x1.y, x1.z, x1.w};
        short8 h, l;
#pragma unroll
        for (int jj = 0; jj < 8; ++jj) {
            unsigned short hh = f2bf(xs[jj]);
            h[jj] = (short)hh;
            l[jj] = (short)f2bf(xs[jj] - bf2f(hh));
        }
        *(short8*)(jb.hi + (size_t)i * 8) = h;
        *(short8*)(jb.lo + (size_t)i * 8) = l;
    }
}

// ---------------------------------------------------------------------------
// bf16x3-split MFMA GEMM: C[M][512] = X[M][512] * W[512][512]^T (+bias).
// BM=BN=128, BK=32, 4 waves (2x2), 4x4 frags of 16x16x32 per wave.
// BF16: X pre-split planes (Xa=hi, Xb=lo); else fp32 X split in staging.
// SPLITOUT: write bf16 hi/lo planes (Ca,Cb); else fp32 C=Ca (+bias).
// Layout (validated by r2 pass): lane=16g+r: A[r][8g+j], B[8g+j][r], D[4g+i][r].
// ---------------------------------------------------------------------------
#define PBK 32
#define PLD 40

template<bool BF16, bool SPLITOUT>
__global__ __launch_bounds__(256) void mfma_gemm(
    const void* Xa0, const void* Xb0, const short* Wh0, const short* Wl0, void* Ca0, void* Cb0,
    const void* Xa1, const void* Xb1, const short* Wh1, const short* Wl1, void* Ca1, void* Cb1,
    const void* Xa2, const void* Xb2, const short* Wh2, const short* Wl2, void* Ca2, void* Cb2,
    const float* __restrict__ bias)
{
    const void* Xa; const void* Xb; const short* Whp; const short* Wlp; void* Cp; void* Cq;
    if (blockIdx.z == 0)      { Xa = Xa0; Xb = Xb0; Whp = Wh0; Wlp = Wl0; Cp = Ca0; Cq = Cb0; }
    else if (blockIdx.z == 1) { Xa = Xa1; Xb = Xb1; Whp = Wh1; Wlp = Wl1; Cp = Ca1; Cq = Cb1; }
    else                      { Xa = Xa2; Xb = Xb2; Whp = Wh2; Wlp = Wl2; Cp = Ca2; Cq = Cb2; }

    const float* Xf = (const float*)Xa;
    const short* Xh = (const short*)Xa;
    const short* Xl = (const short*)Xb;

    __shared__ __align__(16) short Ah[128 * PLD];
    __shared__ __align__(16) short Al[128 * PLD];
    __shared__ __align__(16) short Bh[128 * PLD];
    __shared__ __align__(16) short Bl[128 * PLD];

    const int tid = threadIdx.x;
    const int rowBase = blockIdx.x * 128;
    const int colBase = blockIdx.y * 128;
    const int rs = tid >> 1;
    const int kh = tid & 1;
    const int lane = tid & 63;
    const int wv = tid >> 6;
    const int wm = (wv >> 1) * 64;
    const int wn = (wv & 1) * 64;
    const int g = lane >> 4, r = lane & 15;

    f32x4 acc[4][4];
#pragma unroll
    for (int i = 0; i < 4; ++i)
#pragma unroll
        for (int j = 0; j < 4; ++j) acc[i][j] = (f32x4)(0.f);

    short8 sAh0, sAh1, sAl0, sAl1, sBh0, sBh1, sBl0, sBl1;
    float4 sF0, sF1, sF2, sF3;

    auto loadRegs = [&](int kt) {
        const size_t aoff = (size_t)(rowBase + rs) * 512 + kt * PBK + kh * 16;
        const size_t boff = (size_t)(colBase + rs) * 512 + kt * PBK + kh * 16;
        if constexpr (BF16) {
            sAh0 = *(const short8*)(Xh + aoff); sAh1 = *(const short8*)(Xh + aoff + 8);
            sAl0 = *(const short8*)(Xl + aoff); sAl1 = *(const short8*)(Xl + aoff + 8);
        } else {
            sF0 = *(const float4*)(Xf + aoff);      sF1 = *(const float4*)(Xf + aoff + 4);
            sF2 = *(const float4*)(Xf + aoff + 8);  sF3 = *(const float4*)(Xf + aoff + 12);
        }
        sBh0 = *(const short8*)(Whp + boff); sBh1 = *(const short8*)(Whp + boff + 8);
        sBl0 = *(const short8*)(Wlp + boff); sBl1 = *(const short8*)(Wlp + boff + 8);
    };

    auto stageLDS = [&]() {
        const int lb = rs * PLD + kh * 16;
        if constexpr (BF16) {
            *(short8*)&Ah[lb] = sAh0; *(short8*)&Ah[lb + 8] = sAh1;
            *(short8*)&Al[lb] = sAl0; *(short8*)&Al[lb + 8] = sAl1;
        } else {
            float xs[16] = {sF0.x, sF0.y, sF0.z, sF0.w, sF1.x, sF1.y, sF1.z, sF1.w,
                            sF2.x, sF2.y, sF2.z, sF2.w, sF3.x, sF3.y, sF3.z, sF3.w};
            short8 h0, h1, l0, l1;
#pragma unroll
            for (int jj = 0; jj < 8; ++jj) {
                unsigned short ha = f2bf(xs[jj]);
                h0[jj] = (short)ha; l0[jj] = (short)f2bf(xs[jj] - bf2f(ha));
                unsigned short hb = f2bf(xs[8 + jj]);
                h1[jj] = (short)hb; l1[jj] = (short)f2bf(xs[8 + jj] - bf2f(hb));
            }
            *(short8*)&Ah[lb] = h0; *(short8*)&Ah[lb + 8] = h1;
            *(short8*)&Al[lb] = l0; *(short8*)&Al[lb + 8] = l1;
        }
        *(short8*)&Bh[lb] = sBh0; *(short8*)&Bh[lb + 8] = sBh1;
        *(short8*)&Bl[lb] = sBl0; *(short8*)&Bl[lb + 8] = sBl1;
    };

    loadRegs(0);

    for (int kt = 0; kt < 16; ++kt) {
        __syncthreads();
        stageLDS();
        __syncthreads();
        if (kt < 15) loadRegs(kt + 1);

        short8 fah[4], fal[4], fbh[4], fbl[4];
#pragma unroll
        for (int fm = 0; fm < 4; ++fm) {
            const int off = (wm + fm * 16 + r) * PLD + g * 8;
            fah[fm] = *(const short8*)&Ah[off];
            fal[fm] = *(const short8*)&Al[off];
        }
#pragma unroll
        for (int fn = 0; fn < 4; ++fn) {
            const int off = (wn + fn * 16 + r) * PLD + g * 8;
            fbh[fn] = *(const short8*)&Bh[off];
            fbl[fn] = *(const short8*)&Bl[off];
        }
#pragma unroll
        for (int fm = 0; fm < 4; ++fm)
#pragma unroll
            for (int fn = 0; fn < 4; ++fn) {
                acc[fm][fn] = MFMA16(fah[fm], fbh[fn], acc[fm][fn]);
                acc[fm][fn] = MFMA16(fah[fm], fbl[fn], acc[fm][fn]);
                acc[fm][fn] = MFMA16(fal[fm], fbh[fn], acc[fm][fn]);
            }
    }

    if constexpr (SPLITOUT) {
        short* Ch = (short*)Cp;
        short* Cl2 = (short*)Cq;
#pragma unroll
        for (int fm = 0; fm < 4; ++fm)
#pragma unroll
            for (int fn = 0; fn < 4; ++fn) {
                const int col = colBase + wn + fn * 16 + r;
#pragma unroll
                for (int i = 0; i < 4; ++i) {
                    const int row = rowBase + wm + fm * 16 + g * 4 + i;
                    float v = acc[fm][fn][i];
                    unsigned u = __float_as_uint(v);
                    unsigned hi = u & 0xFFFF0000u;
                    float lf = v - __uint_as_float(hi);
                    Ch[(size_t)row * 512 + col]  = (short)(hi >> 16);
                    Cl2[(size_t)row * 512 + col] = (short)(__float_as_uint(lf) >> 16);
                }
            }
    } else {
        float* C = (float*)Cp;
        float bv[4];
#pragma unroll
        for (int fn = 0; fn < 4; ++fn)
            bv[fn] = bias ? bias[colBase + wn + fn * 16 + r] : 0.f;
#pragma unroll
        for (int fm = 0; fm < 4; ++fm)
#pragma unroll
            for (int fn = 0; fn < 4; ++fn) {
                const int col = colBase + wn + fn * 16 + r;
#pragma unroll
                for (int i = 0; i < 4; ++i) {
                    const int row = rowBase + wm + fm * 16 + g * 4 + i;
                    C[(size_t)row * 512 + col] = acc[fm][fn][i] + bv[fn];
                }
            }
    }
}

// ---------------------------------------------------------------------------
// bf16x3-split MFMA flash attention.
// Block = 128 q rows of one (b,h), 4 waves x 32 q. K-tile = 64 keys.
// S^T = K*Q^T and out^T = V^T*P^T via 32x32x16 MFMA: every operand is a
// row-contiguous ds_read_b128; each lane owns one full q-row of scores
// (col = lane&31), so softmax = local reduce + one shfl_xor(32), and the
// online-softmax alpha/l are per-lane scalars for both S and out accs.
// D layout (m74/m101): row=(reg&3)+8*(reg>>2)+4*(lane>>5)(+32*fr), col=lane&31.
// LDS pitch 72 shorts: rows 16B-aligned, bank starts evenly spread.
// ---------------------------------------------------------------------------
#define ATP 72

__global__ __launch_bounds__(256) void attn_mfma(
    const short* __restrict__ Qh, const short* __restrict__ Ql,
    const short* __restrict__ Kh, const short* __restrict__ Kl,
    const short* __restrict__ Vh, const short* __restrict__ Vl,
    const int* __restrict__ mask,
    short* __restrict__ Oh, short* __restrict__ Ol)
{
    const int S = 2048;
    const float scale = 0.04419417382415922f;  // 1/sqrt(512)

    __shared__ __align__(16) short Ksh[64 * ATP], Ksl[64 * ATP];
    __shared__ __align__(16) short Vth[64 * ATP], Vtl[64 * ATP];
    __shared__ __align__(16) short Ph[4][32 * ATP], Pl[4][32 * ATP];
    __shared__ unsigned Msk[2];

    const int t = threadIdx.x;
    const int w = t >> 6;
    const int lo5 = t & 31;            // within-wave col (q for S, q for out^T)
    const int hi1 = (t >> 5) & 1;      // k-half selector
    const int qb0 = blockIdx.x * 128;
    const int bh = blockIdx.y;
    const int b = bh >> 3, h = bh & 7;
    const int base4 = 4 * hi1;

    // ---- Q fragments, held in registers for the whole kernel
    short8 qf[4][2];
    {
        const size_t qrow = ((size_t)(b * S + qb0 + w * 32 + lo5)) * 512 + h * 64;
#pragma unroll
        for (int ks = 0; ks < 4; ++ks) {
            qf[ks][0] = *(const short8*)(Qh + qrow + 8 * hi1 + 16 * ks);
            qf[ks][1] = *(const short8*)(Ql + qrow + 8 * hi1 + 16 * ks);
        }
    }

    float m_ = -3.0e38f, l_ = 0.f;
    f32x16 acc[2];
    acc[0] = (f32x16)(0.f); acc[1] = (f32x16)(0.f);

    // ---- tile prefetch registers
    const int krow = t >> 2, ksq = t & 3;
    const int vk0 = (t & 31) * 2, vdb = (t >> 5) * 8;
    short8 pk[2][2], pv[2][2];
    int pm = 1;

    auto loadTile = [&](int kt) {
        const size_t kro = ((size_t)(b * S + kt * 64 + krow)) * 512 + h * 64;
        pk[0][0] = *(const short8*)(Kh + kro + ksq * 8);
        pk[0][1] = *(const short8*)(Kh + kro + ksq * 8 + 32);
        pk[1][0] = *(const short8*)(Kl + kro + ksq * 8);
        pk[1][1] = *(const short8*)(Kl + kro + ksq * 8 + 32);
        const size_t vro = ((size_t)(b * S + kt * 64 + vk0)) * 512 + h * 64 + vdb;
        pv[0][0] = *(const short8*)(Vh + vro);
        pv[0][1] = *(const short8*)(Vh + vro + 512);
        pv[1][0] = *(const short8*)(Vl + vro);
        pv[1][1] = *(const short8*)(Vl + vro + 512);
        if (t < 64) pm = mask[b * S + kt * 64 + t];
    };

    loadTile(0);

    for (int kt = 0; kt < 32; ++kt) {
        __syncthreads();   // previous tile's frag reads done
        // ---- stage K (row-major) and V (transposed) from prefetch regs
        *(short8*)&Ksh[krow * ATP + ksq * 8]      = pk[0][0];
        *(short8*)&Ksh[krow * ATP + ksq * 8 + 32] = pk[0][1];
        *(short8*)&Ksl[krow * ATP + ksq * 8]      = pk[1][0];
        *(short8*)&Ksl[krow * ATP + ksq * 8 + 32] = pk[1][1];
#pragma unroll
        for (int dd = 0; dd < 8; ++dd) {
            *(int*)&Vth[(vdb + dd) * ATP + vk0] =
                (unsigned)(unsigned short)pv[0][0][dd] |
                ((unsigned)(unsigned short)pv[0][1][dd] << 16);
            *(int*)&Vtl[(vdb + dd) * ATP + vk0] =
                (unsigned)(unsigned short)pv[1][0][dd] |
                ((unsigned)(unsigned short)pv[1][1][dd] << 16);
        }
        if (t < 64) {
            unsigned long long bm = __ballot(pm != 0);
            if (t == 0) { Msk[0] = (unsigned)bm; Msk[1] = (unsigned)(bm >> 32); }
        }
        __syncthreads();

        if (kt < 31) loadTile(kt + 1);  // retires under compute

        const unsigned mw0 = Msk[0], mw1 = Msk[1];

        // ---- S^T = K * Q^T  (A = K rows lo5+32fr, B = Q)
        f32x16 sacc[2];
        sacc[0] = (f32x16)(0.f); sacc[1] = (f32x16)(0.f);
#pragma unroll
        for (int ks = 0; ks < 4; ++ks) {
            const int co = 8 * hi1 + 16 * ks;
#pragma unroll
            for (int fr = 0; fr < 2; ++fr) {
                short8 ah = *(const short8*)&Ksh[(lo5 + 32 * fr) * ATP + co];
                short8 al = *(const short8*)&Ksl[(lo5 + 32 * fr) * ATP + co];
                sacc[fr] = MFMA32(ah, qf[ks][0], sacc[fr]);
                sacc[fr] = MFMA32(ah, qf[ks][1], sacc[fr]);
                sacc[fr] = MFMA32(al, qf[ks][0], sacc[fr]);
            }
        }

        // ---- mask + scale + online softmax (all 32 values are row q=lo5)
        float pvv[2][16];
        float mt = -3.0e38f;
#pragma unroll
        for (int fr = 0; fr < 2; ++fr) {
            const unsigned mw = fr ? mw1 : mw0;
#pragma unroll
            for (int reg = 0; reg < 16; ++reg) {
                const int sh = (reg & 3) + 8 * (reg >> 2) + base4;
                float s = ((mw >> sh) & 1u) ? sacc[fr][reg] * scale : -1.0e20f;
                pvv[fr][reg] = s;
                mt = fmaxf(mt, s);
            }
        }
        mt = fmaxf(mt, __shfl_xor(mt, 32));
        const float mn = fmaxf(m_, mt);
        const float alpha = __expf(m_ - mn);
        m_ = mn;
        float ps = 0.f;
#pragma unroll
        for (int fr = 0; fr < 2; ++fr)
#pragma unroll
            for (int reg = 0; reg < 16; ++reg) {
                const float e = __expf(pvv[fr][reg] - mn);
                pvv[fr][reg] = e;
                ps += e;
            }
        ps += __shfl_xor(ps, 32);
        l_ = l_ * alpha + ps;
        acc[0] *= alpha;
        acc[1] *= alpha;

        // ---- write P (trunc hi/lo bf16) to per-wave LDS: P[q=lo5][key]
#pragma unroll
        for (int fr = 0; fr < 2; ++fr)
#pragma unroll
            for (int rq = 0; rq < 4; ++rq) {
                const float v0 = pvv[fr][rq * 4 + 0], v1 = pvv[fr][rq * 4 + 1];
                const float v2 = pvv[fr][rq * 4 + 2], v3 = pvv[fr][rq * 4 + 3];
                const unsigned u0 = __float_as_uint(v0), u1 = __float_as_uint(v1);
                const unsigned u2 = __float_as_uint(v2), u3 = __float_as_uint(v3);
                int2 hw;
                hw.x = (int)((u1 & 0xFFFF0000u) | (u0 >> 16));
                hw.y = (int)((u3 & 0xFFFF0000u) | (u2 >> 16));
                const float a0 = v0 - __uint_as_float(u0 & 0xFFFF0000u);
                const float a1 = v1 - __uint_as_float(u1 & 0xFFFF0000u);
                const float a2 = v2 - __uint_as_float(u2 & 0xFFFF0000u);
                const float a3 = v3 - __uint_as_float(u3 & 0xFFFF0000u);
                int2 lw;
                lw.x = (int)((__float_as_uint(a1) & 0xFFFF0000u) | (__float_as_uint(a0) >> 16));
                lw.y = (int)((__float_as_uint(a3) & 0xFFFF0000u) | (__float_as_uint(a2) >> 16));
                const int off = lo5 * ATP + 8 * rq + base4 + 32 * fr;
                *(int2*)&Ph[w][off] = hw;
                *(int2*)&Pl[w][off] = lw;
            }

        // ---- out^T += V^T * P^T  (A = Vt rows lo5+32fr, B = P)
#pragma unroll
        for (int ks = 0; ks < 4; ++ks) {
            const int co = 8 * hi1 + 16 * ks;
            short8 pbh = *(const short8*)&Ph[w][lo5 * ATP + co];
            short8 pbl = *(const short8*)&Pl[w][lo5 * ATP + co];
#pragma unroll
            for (int fr = 0; fr < 2; ++fr) {
                short8 vah = *(const short8*)&Vth[(lo5 + 32 * fr) * ATP + co];
                short8 val = *(const short8*)&Vtl[(lo5 + 32 * fr) * ATP + co];
                acc[fr] = MFMA32(vah, pbh, acc[fr]);
                acc[fr] = MFMA32(vah, pbl, acc[fr]);
                acc[fr] = MFMA32(val, pbh, acc[fr]);
            }
        }
    }

    // ---- epilogue: normalize, trunc-split, store planes (4 consecutive d)
    const float inv = 1.0f / l_;
    const size_t orow = ((size_t)(b * S + qb0 + w * 32 + lo5)) * 512 + h * 64;
#pragma unroll
    for (int fr = 0; fr < 2; ++fr)
#pragma unroll
        for (int rq = 0; rq < 4; ++rq) {
            float v[4];
            unsigned uh[4], ulo[4];
#pragma unroll
            for (int i = 0; i < 4; ++i) {
                v[i] = acc[fr][rq * 4 + i] * inv;
                unsigned u = __float_as_uint(v[i]);
                uh[i] = u & 0xFFFF0000u;
                ulo[i] = __float_as_uint(v[i] - __uint_as_float(uh[i]));
            }
            int2 hw, lw;
            hw.x = (int)((uh[1]) | (uh[0] >> 16));
            hw.y = (int)((uh[3]) | (uh[2] >> 16));
            lw.x = (int)((ulo[1] & 0xFFFF0000u) | (ulo[0] >> 16));
            lw.y = (int)((ulo[3] & 0xFFFF0000u) | (ulo[2] >> 16));
            const size_t off = orow + 8 * rq + base4 + 32 * fr;
            *(int2*)&Oh[off] = hw;
            *(int2*)&Ol[off] = lw;
        }
}

// ---------------------------------------------------------------------------
extern "C" void kernel_launch(void* const* d_in, const int* in_sizes, int n_in,
                              void* d_out, int out_size, void* d_ws, size_t ws_size,
                              hipStream_t stream) {
    const float* values = (const float*)d_in[0];
    const float* keys   = (const float*)d_in[1];
    const float* query  = (const float*)d_in[2];
    const int*   mask   = (const int*)d_in[3];
    const float* Wv     = (const float*)d_in[4];
    const float* Wk     = (const float*)d_in[5];
    const float* Wq     = (const float*)d_in[6];
    const float* Wo     = (const float*)d_in[7];
    const float* bo     = (const float*)d_in[8];
    float* out = (float*)d_out;

    const size_t MB = 1024 * 1024;
    char* wsb = (char*)d_ws;
    const size_t NPLANE = (size_t)8192 * 512;   // 4M shorts = 8 MB
    short* Qhp = (short*)(wsb);
    short* Qlp = (short*)(wsb + 8 * MB);
    short* Khp = (short*)(wsb + 16 * MB);
    short* Klp = (short*)(wsb + 24 * MB);
    short* Vhp = (short*)(wsb + 32 * MB);
    short* Vlp = (short*)(wsb + 40 * MB);
    short* Ohp = (short*)(wsb + 48 * MB);
    short* Olp = (short*)(wsb + 56 * MB);
    short* Wqh = (short*)(wsb + 64 * MB);   short* Wql = Wqh + 262144;
    short* Wkh = Wql + 262144;              short* Wkl = Wkh + 262144;
    short* Wvh = Wkl + 262144;              short* Wvl = Wvh + 262144;
    short* Woh = Wvl + 262144;              short* Wol = Woh + 262144;
    (void)NPLANE; (void)ws_size; (void)in_sizes; (void)n_in; (void)out_size;

    const int nW = 512 * 512 / 8;
    ConvArgs ca;
    ca.j[0] = {Wq, Wqh, Wql, nW};
    ca.j[1] = {Wk, Wkh, Wkl, nW};
    ca.j[2] = {Wv, Wvh, Wvl, nW};
    ca.j[3] = {Wo, Woh, Wol, nW};
    conv_split<<<dim3(128, 1, 4), 256, 0, stream>>>(ca);

    // q/k/v projections: fp32 X in, bf16 hi/lo planes out
    mfma_gemm<false, true><<<dim3(64, 4, 3), 256, 0, stream>>>(
        query,  nullptr, Wqh, Wql, Qhp, Qlp,
        keys,   nullptr, Wkh, Wkl, Khp, Klp,
        values, nullptr, Wvh, Wvl, Vhp, Vlp, nullptr);

    // fused attention on bf16 planes
    attn_mfma<<<dim3(16, 32), 256, 0, stream>>>(
        Qhp, Qlp, Khp, Klp, Vhp, Vlp, mask, Ohp, Olp);

    // output projection: plane input, fp32 out + bias
    mfma_gemm<true, false><<<dim3(64, 4, 1), 256, 0, stream>>>(
        Ohp, Olp, Woh, Wol, out, nullptr,
        Ohp, Olp, Woh, Wol, out, nullptr,
        Ohp, Olp, Woh, Wol, out, nullptr, bo);
}